// Round 1
// baseline (698.755 us; speedup 1.0000x reference)
//
#include <hip/hip_runtime.h>
#include <math.h>

#define LSEQ 512
#define CS 384
#define CZ 256
#define HD 16
#define NH 12
#define NQ 4
#define NV 8
#define NALL 1152   // 192*3 + 144*2 + 288
#define SHID 3648   // NH * 304
#define OFF_Q 0
#define OFF_K 192
#define OFF_V 384
#define OFF_QP 576
#define OFF_KP 720
#define OFF_VP 864

#define WC_CONST 0.2357022603955158f  // sqrt(2/(9*4))
#define WL_CONST 0.5773502691896258f  // sqrt(1/3)

typedef __attribute__((ext_vector_type(8))) short bf16x8;
typedef __attribute__((ext_vector_type(4))) float f32x4;

__device__ __forceinline__ short f2bf(float f) {
  unsigned u = __builtin_bit_cast(unsigned, f);
  unsigned r = (u + 0x7FFF + ((u >> 16) & 1)) >> 16;
  return (short)r;
}

// ---------------- prep: R, t, c_h, padded bf16 Wb ----------------
__global__ void k_prep(const float* quat, const float* trsl, const float* scale,
                       const float* Wb, float* R, float* T, float* CH,
                       unsigned short* WBP) {
  int t = threadIdx.x;
  if (t < LSEQ) {
    float w = quat[t*4+0], x = quat[t*4+1], y = quat[t*4+2], z = quat[t*4+3];
    float inv = 1.0f / sqrtf(w*w + x*x + y*y + z*z);
    w *= inv; x *= inv; y *= inv; z *= inv;
    float* r = R + t*9;
    r[0] = 1.f - 2.f*(y*y + z*z); r[1] = 2.f*(x*y - w*z);       r[2] = 2.f*(x*z + w*y);
    r[3] = 2.f*(x*y + w*z);       r[4] = 1.f - 2.f*(x*x + z*z); r[5] = 2.f*(y*z - w*x);
    r[6] = 2.f*(x*z - w*y);       r[7] = 2.f*(y*z + w*x);       r[8] = 1.f - 2.f*(x*x + y*y);
    T[t*3+0] = trsl[t*3+0]; T[t*3+1] = trsl[t*3+1]; T[t*3+2] = trsl[t*3+2];
  }
  if (t < NH) {
    float sc = scale[t];
    float sp = (sc > 20.f) ? sc : logf(1.f + expf(sc));
    CH[t] = 0.5f * WC_CONST * sp;
  }
  if (t < CZ) {
    #pragma unroll
    for (int h = 0; h < 16; h++)
      WBP[t*16 + h] = (h < NH) ? (unsigned short)f2bf(Wb[t*NH + h]) : (unsigned short)0;
  }
}

// ---------------- concat weights ----------------
__global__ void k_concat(const float* Wq, const float* Wk, const float* Wv,
                         const float* Wqp, const float* Wkp, const float* Wvp,
                         float* Wcat) {
  int idx = blockIdx.x * 256 + threadIdx.x;
  if (idx >= CS * NALL) return;
  int r = idx / NALL, c = idx % NALL;
  float v;
  if (c < 192)       v = Wq [r*192 + c];
  else if (c < 384)  v = Wk [r*192 + (c-192)];
  else if (c < 576)  v = Wv [r*192 + (c-384)];
  else if (c < 720)  v = Wqp[r*144 + (c-576)];
  else if (c < 864)  v = Wkp[r*144 + (c-720)];
  else               v = Wvp[r*288 + (c-864)];
  Wcat[idx] = v;
}

// ---------------- f32 GEMM with register prefetch; N,M multiples of 64 ----------------
// grid (N/64, M/64, splitk). splitk>1 accumulates via atomics into zeroed C.
__global__ __launch_bounds__(256) void k_gemm(
    const float* A, const float* B, float* C, const float* bias,
    int K, int lda, int ldb, int ldc, int splitk, int relu, int reluA) {
  int ks = blockIdx.z;
  int Ksub = K / splitk;
  int kbeg = ks * Ksub, kend = kbeg + Ksub;

  __shared__ __align__(16) float As[16][68];
  __shared__ __align__(16) float Bs[16][68];
  int t = threadIdx.x;
  int m0 = blockIdx.y * 64, n0 = blockIdx.x * 64;
  int arow = t >> 2,  akq = (t & 3) * 4;
  int bkk  = t >> 4,  bnq = (t & 15) * 4;
  int ty = (t >> 4) * 4, tx = (t & 15) * 4;
  float acc[4][4];
  #pragma unroll
  for (int r = 0; r < 4; r++)
    #pragma unroll
    for (int c = 0; c < 4; c++) acc[r][c] = 0.f;

  const float* aptr  = A + (long)(m0 + arow) * lda + akq;
  const float* bbase = B + n0 + bnq;
  float4 av = *(const float4*)&aptr[kbeg];
  float4 bv = *(const float4*)&bbase[(long)(kbeg + bkk) * ldb];

  for (int kb = kbeg; kb < kend; kb += 16) {
    float4 a_cur = av, b_cur = bv;
    if (reluA) {
      a_cur.x = fmaxf(a_cur.x, 0.f); a_cur.y = fmaxf(a_cur.y, 0.f);
      a_cur.z = fmaxf(a_cur.z, 0.f); a_cur.w = fmaxf(a_cur.w, 0.f);
    }
    __syncthreads();
    As[akq+0][arow] = a_cur.x; As[akq+1][arow] = a_cur.y;
    As[akq+2][arow] = a_cur.z; As[akq+3][arow] = a_cur.w;
    *(float4*)&Bs[bkk][bnq] = b_cur;
    __syncthreads();
    if (kb + 16 < kend) {
      av = *(const float4*)&aptr[kb + 16];
      bv = *(const float4*)&bbase[(long)(kb + 16 + bkk) * ldb];
    }
    #pragma unroll
    for (int kk = 0; kk < 16; kk++) {
      float4 a4 = *(float4*)&As[kk][ty];
      float4 b4 = *(float4*)&Bs[kk][tx];
      acc[0][0] += a4.x*b4.x; acc[0][1] += a4.x*b4.y; acc[0][2] += a4.x*b4.z; acc[0][3] += a4.x*b4.w;
      acc[1][0] += a4.y*b4.x; acc[1][1] += a4.y*b4.y; acc[1][2] += a4.y*b4.z; acc[1][3] += a4.y*b4.w;
      acc[2][0] += a4.z*b4.x; acc[2][1] += a4.z*b4.y; acc[2][2] += a4.z*b4.z; acc[2][3] += a4.z*b4.w;
      acc[3][0] += a4.w*b4.x; acc[3][1] += a4.w*b4.y; acc[3][2] += a4.w*b4.z; acc[3][3] += a4.w*b4.w;
    }
  }

  if (splitk == 1) {
    #pragma unroll
    for (int r = 0; r < 4; r++) {
      int m = m0 + ty + r;
      #pragma unroll
      for (int c = 0; c < 4; c++) {
        int n = n0 + tx + c;
        float v = acc[r][c] + (bias ? bias[n] : 0.f);
        if (relu) v = fmaxf(v, 0.f);
        C[(long)m * ldc + n] = v;
      }
    }
  } else {
    #pragma unroll
    for (int r = 0; r < 4; r++) {
      int m = m0 + ty + r;
      #pragma unroll
      for (int c = 0; c < 4; c++) {
        int n = n0 + tx + c;
        float v = acc[r][c] + ((ks == 0 && bias) ? bias[n] : 0.f);
        atomicAdd(&C[(long)m * ldc + n], v);
      }
    }
  }
}

// ---------------- rigid transforms, 3 concurrent tasks ----------------
// grid (24, 3) x 256; idx = (h, l) l fastest -> coalesced writes
__global__ void k_trans(const float* P, const float* R, const float* T,
                        float* QPP, float* KT, float* KPT, float* VBT) {
  int task = blockIdx.y;
  int idx = blockIdx.x * 256 + threadIdx.x;
  if (idx >= LSEQ * NH) return;
  int h = idx / LSEQ, l = idx % LSEQ;
  const float* r = R + l*9;
  float t0 = T[l*3], t1 = T[l*3+1], t2 = T[l*3+2];
  const float* prow = P + (long)l * NALL;
  if (task == 0) {
    #pragma unroll
    for (int pq = 0; pq < NQ; pq++) {
      const float* x = prow + OFF_QP + h*12 + pq*3;
      float a = x[0], b = x[1], c = x[2];
      float* o = QPP + l*144 + h*12 + pq*3;
      o[0] = r[0]*a + r[1]*b + r[2]*c + t0;
      o[1] = r[3]*a + r[4]*b + r[5]*c + t1;
      o[2] = r[6]*a + r[7]*b + r[8]*c + t2;
    }
    #pragma unroll
    for (int d = 0; d < HD; d++)
      KT[(h*HD + d)*LSEQ + l] = prow[OFF_K + h*HD + d];
  } else if (task == 1) {
    #pragma unroll
    for (int pq = 0; pq < NQ; pq++) {
      const float* x = prow + OFF_KP + h*12 + pq*3;
      float a = x[0], b = x[1], c = x[2];
      KPT[(h*12 + pq*3 + 0)*LSEQ + l] = r[0]*a + r[1]*b + r[2]*c + t0;
      KPT[(h*12 + pq*3 + 1)*LSEQ + l] = r[3]*a + r[4]*b + r[5]*c + t1;
      KPT[(h*12 + pq*3 + 2)*LSEQ + l] = r[6]*a + r[7]*b + r[8]*c + t2;
    }
  } else {
    // VBT[(h*40+p)][l] : p<16 = v, p>=16 = vpp
    #pragma unroll
    for (int d = 0; d < 16; d++)
      VBT[((long)(h*40 + d))*LSEQ + l] = prow[OFF_V + h*16 + d];
    #pragma unroll
    for (int pv = 0; pv < NV; pv++) {
      const float* x = prow + OFF_VP + h*24 + pv*3;
      float a = x[0], b = x[1], c = x[2];
      VBT[((long)(h*40 + 16 + 3*pv + 0))*LSEQ + l] = r[0]*a + r[1]*b + r[2]*c + t0;
      VBT[((long)(h*40 + 16 + 3*pv + 1))*LSEQ + l] = r[3]*a + r[4]*b + r[5]*c + t1;
      VBT[((long)(h*40 + 16 + 3*pv + 2))*LSEQ + l] = r[6]*a + r[7]*b + r[8]*c + t2;
    }
  }
}

// ---------------- logits sans bias: LG[i][h][j] = WL*(qk/4 - ch*d2) ----------------
// grid 512 (one i per block), 512 threads (j). 2 blocks/CU -> 50% occ ceiling.
__global__ __launch_bounds__(512) void k_logit(const float* P, const float* QPP,
    const float* KT, const float* KPT, const float* CH, float* LG) {
  int i = blockIdx.x;
  int j = threadIdx.x;
  #pragma unroll
  for (int h = 0; h < NH; h++) {
    float kreg[16];
    #pragma unroll
    for (int d = 0; d < 16; d++) kreg[d] = KT[(h*16 + d)*LSEQ + j];
    float kp[12];
    #pragma unroll
    for (int p = 0; p < 12; p++) kp[p] = KPT[(h*12 + p)*LSEQ + j];
    float ch = CH[h];
    const float* q  = P + (long)i*NALL + OFF_Q + h*HD;   // uniform -> s_load
    const float* qp = QPP + i*144 + h*12;                // uniform -> s_load
    float dot = 0.f;
    #pragma unroll
    for (int d = 0; d < 16; d++) dot += q[d] * kreg[d];
    float d2 = 0.f;
    #pragma unroll
    for (int p = 0; p < 12; p++) { float dd = qp[p] - kp[p]; d2 += dd*dd; }
    LG[((long)i*NH + h)*LSEQ + j] = WL_CONST * (0.25f*dot - ch*d2);
  }
}

// ---------------- fused bias + softmax + op + ov/ovp, j-split for occupancy ----------------
// grid (512, 2), 256 threads (4 waves). Each block covers 256 j (4 tiles of 64).
// Unnormalized partials accumulate via atomicAdd into zeroed SH(op region)/OVT/SSUM.
// Per 64-j tile:
//   MFMA: b = z_tile @ Wb  (bf16), e = exp(LG + WL*b) -> LDS
//   VALU: accop[c][h] += e*z (z re-read, L2-hot); accv[(h,p)] += e*VBT
__global__ __launch_bounds__(256) void k_fused(const float* zin,
    const unsigned short* WBP, const float* LG, const float* VBT,
    float* SH, float* OVT, float* SSUM) {
  __shared__ __align__(16) float lgs[NH][264];
  __shared__ __align__(16) float es[NH][68];
  __shared__ float sred[4][NH];
  int i = blockIdx.x, js = blockIdx.y, t = threadIdx.x;
  int jbase = js * 256;
  int w = t >> 6, l = t & 63;
  int r = l & 15, kg = l >> 4;

  // stage this block's LG half (12x256) coalesced
  const float* lgsrc = LG + (long)i * NH * LSEQ + jbase;
  #pragma unroll
  for (int idx = t; idx < NH*256/4; idx += 256) {
    int h = idx >> 6, q4 = idx & 63;
    *(float4*)&lgs[h][q4*4] = *(const float4*)&lgsrc[h*LSEQ + q4*4];
  }

  // Wb B-frags (col h = r, k = kg*8+jj within kt*32 chunk)
  bf16x8 bfrag[8];
  #pragma unroll
  for (int kt = 0; kt < 8; kt++)
    #pragma unroll
    for (int jj = 0; jj < 8; jj++)
      bfrag[kt][jj] = (short)WBP[(kt*32 + kg*8 + jj)*16 + r];

  float accop[NH];
  #pragma unroll
  for (int h = 0; h < NH; h++) accop[h] = 0.f;
  int pair0 = t, pair1 = t + 256;             // (h,p) flat, 480 total
  int h0 = pair0 / 40;
  int h1 = pair1 / 40;
  float accv0 = 0.f, accv1 = 0.f;
  float sparts = 0.f;
  int hh = (r < NH) ? r : 0;

  __syncthreads();   // lgs ready

  for (int jt = 0; jt < 256; jt += 64) {
    int j0 = jt + w*16;            // within this block's half
    int j0g = jbase + j0;          // global j for z reads
    // ---- MFMA phase: b for rows j0g..j0g+15, col h=r ----
    const float* zrow = zin + ((long)i*LSEQ + j0g + r)*CZ + kg*8;
    f32x4 acc = {0.f, 0.f, 0.f, 0.f};
    #pragma unroll
    for (int kt = 0; kt < 8; kt++) {
      float4 z0 = *(const float4*)(zrow + kt*32);
      float4 z1 = *(const float4*)(zrow + kt*32 + 4);
      bf16x8 af;
      af[0] = f2bf(z0.x); af[1] = f2bf(z0.y); af[2] = f2bf(z0.z); af[3] = f2bf(z0.w);
      af[4] = f2bf(z1.x); af[5] = f2bf(z1.y); af[6] = f2bf(z1.z); af[7] = f2bf(z1.w);
      acc = __builtin_amdgcn_mfma_f32_16x16x32_bf16(af, bfrag[kt], acc, 0, 0, 0);
    }
    // e = exp(LG + WL*b); D-layout: col h=r, row j = j0 + kg*4 + reg
    float4 lgv = *(float4*)&lgs[hh][j0 + kg*4];
    float e0 = __expf(lgv.x + WL_CONST*acc[0]);
    float e1 = __expf(lgv.y + WL_CONST*acc[1]);
    float e2 = __expf(lgv.z + WL_CONST*acc[2]);
    float e3 = __expf(lgv.w + WL_CONST*acc[3]);
    if (r < NH) {
      sparts += e0 + e1 + e2 + e3;
      *(float4*)&es[r][w*16 + kg*4] = make_float4(e0, e1, e2, e3);
    }
    __syncthreads();   // es ready
    // ---- op phase: c = t, z re-read (L2-hot) ----
    const float* zc = zin + ((long)i*LSEQ + jbase + jt)*CZ + t;
    #pragma unroll 4
    for (int jj = 0; jj < 64; jj += 4) {
      float z0 = zc[(jj+0)*CZ], z1 = zc[(jj+1)*CZ];
      float z2 = zc[(jj+2)*CZ], z3 = zc[(jj+3)*CZ];
      #pragma unroll
      for (int h = 0; h < NH; h++) {
        float4 ev = *(float4*)&es[h][jj];
        accop[h] += ev.x*z0 + ev.y*z1 + ev.z*z2 + ev.w*z3;
      }
    }
    // ---- ovt phase ----
    {
      const float* vb0 = VBT + ((long)pair0)*LSEQ + jbase + jt;
      #pragma unroll
      for (int jj = 0; jj < 64; jj += 4) {
        float4 vv = *(const float4*)&vb0[jj];
        float4 ev = *(float4*)&es[h0][jj];
        accv0 += vv.x*ev.x + vv.y*ev.y + vv.z*ev.z + vv.w*ev.w;
      }
      if (pair1 < 480) {
        const float* vb1 = VBT + ((long)pair1)*LSEQ + jbase + jt;
        #pragma unroll
        for (int jj = 0; jj < 64; jj += 4) {
          float4 vv = *(const float4*)&vb1[jj];
          float4 ev = *(float4*)&es[h1][jj];
          accv1 += vv.x*ev.x + vv.y*ev.y + vv.z*ev.z + vv.w*ev.w;
        }
      }
    }
    __syncthreads();   // es consumed before next tile overwrites
  }

  // partial denominators -> SSUM (stride 16 per i)
  sparts += __shfl_xor(sparts, 16);
  sparts += __shfl_xor(sparts, 32);
  if (l < NH) sred[w][l] = sparts;
  __syncthreads();
  if (t < NH)
    atomicAdd(&SSUM[i*16 + t], sred[0][t] + sred[1][t] + sred[2][t] + sred[3][t]);

  // unnormalized partials
  float* sh = SH + (long)i * SHID + t;
  #pragma unroll
  for (int h = 0; h < NH; h++) atomicAdd(&sh[h * 304], accop[h]);
  atomicAdd(&OVT[(long)i*480 + pair0], accv0);
  if (pair1 < 480) atomicAdd(&OVT[(long)i*480 + pair1], accv1);
}

// ---------------- normalize op region of SH ----------------
__global__ __launch_bounds__(256) void k_opnorm(const float* SSUM, float* SH) {
  int i = blockIdx.x, t = threadIdx.x;
  float* sh = SH + (long)i * SHID + t;
  #pragma unroll
  for (int h = 0; h < NH; h++) {
    float inv = 1.0f / SSUM[i*16 + h];
    sh[h * 304] *= inv;
  }
}

// ---------------- ovp inverse transform + norm + shid fill ----------------
__global__ void k_ovp(const float* OVT, const float* SSUM, const float* R,
                      const float* T, float* SH) {
  int idx = blockIdx.x * 256 + threadIdx.x;
  if (idx >= LSEQ * NH) return;
  int l = idx / NH, h = idx % NH;
  float inv = 1.0f / SSUM[l*16 + h];
  const float* o = OVT + (long)l*480 + h*40;
  float* sh = SH + (long)l * SHID + h * 304;
  #pragma unroll
  for (int d = 0; d < 16; d++) sh[256 + d] = o[d] * inv;
  const float* r = R + l*9;
  float t0 = T[l*3], t1 = T[l*3+1], t2 = T[l*3+2];
  #pragma unroll
  for (int v = 0; v < NV; v++) {
    float a = o[16+3*v+0]*inv - t0, b = o[16+3*v+1]*inv - t1, c = o[16+3*v+2]*inv - t2;
    float x = r[0]*a + r[3]*b + r[6]*c;   // R^T
    float y = r[1]*a + r[4]*b + r[7]*c;
    float zz= r[2]*a + r[5]*b + r[8]*c;
    sh[272 + 3*v + 0] = x;
    sh[272 + 3*v + 1] = y;
    sh[272 + 3*v + 2] = zz;
    sh[296 + v] = sqrtf(x*x + y*y + zz*zz);
  }
}

// ---------------- layernorm: out = LN(res + y) * g + b ----------------
__global__ __launch_bounds__(384) void k_ln(const float* res, const float* y,
                                            const float* g, const float* b, float* out) {
  int l = blockIdx.x, t = threadIdx.x;
  __shared__ float red1[6], red2[6];
  __shared__ float mv[2];
  float x = res[(long)l * CS + t] + y[(long)l * CS + t];
  float s = x, s2 = x * x;
  #pragma unroll
  for (int off = 32; off >= 1; off >>= 1) { s += __shfl_xor(s, off); s2 += __shfl_xor(s2, off); }
  if ((t & 63) == 0) { red1[t >> 6] = s; red2[t >> 6] = s2; }
  __syncthreads();
  if (t == 0) {
    float ss = 0.f, ss2 = 0.f;
    #pragma unroll
    for (int u = 0; u < 6; u++) { ss += red1[u]; ss2 += red2[u]; }
    float m = ss / CS;
    float var = ss2 / CS - m * m;
    mv[0] = m; mv[1] = 1.0f / sqrtf(var + 1e-5f);
  }
  __syncthreads();
  out[(long)l * CS + t] = (x - mv[0]) * mv[1] * g[t] + b[t];
}

// ---------------- launcher ----------------
extern "C" void kernel_launch(void* const* d_in, const int* in_sizes, int n_in,
                              void* d_out, int out_size, void* d_ws, size_t ws_size,
                              hipStream_t stream) {
  const float* s    = (const float*)d_in[0];
  const float* z    = (const float*)d_in[1];
  const float* quat = (const float*)d_in[2];
  const float* trsl = (const float*)d_in[3];
  const float* Wq   = (const float*)d_in[4];
  const float* Wk   = (const float*)d_in[5];
  const float* Wv   = (const float*)d_in[6];
  const float* Wqp  = (const float*)d_in[7];
  const float* Wkp  = (const float*)d_in[8];
  const float* Wvp  = (const float*)d_in[9];
  const float* Wb   = (const float*)d_in[10];
  const float* Ws   = (const float*)d_in[11];
  const float* bs   = (const float*)d_in[12];
  const float* scale= (const float*)d_in[13];
  const float* g1   = (const float*)d_in[14];
  const float* b1   = (const float*)d_in[15];
  const float* Wm1  = (const float*)d_in[16];
  const float* bm1  = (const float*)d_in[17];
  const float* Wm2  = (const float*)d_in[18];
  const float* bm2  = (const float*)d_in[19];
  const float* Wm3  = (const float*)d_in[20];
  const float* bm3  = (const float*)d_in[21];
  const float* g2   = (const float*)d_in[22];
  const float* b2   = (const float*)d_in[23];
  float* out = (float*)d_out;

  float* p = (float*)d_ws;
  float* R    = p; p += 512*9;
  float* T    = p; p += 512*3;
  float* CH   = p; p += 16;
  unsigned short* WBP = (unsigned short*)p; p += (CZ*16)/2;
  float* Wcat = p; p += (long)CS*NALL;
  float* QPP  = p; p += LSEQ*144;
  float* KT   = p; p += NH*HD*LSEQ;
  float* KPT  = p; p += NH*12*LSEQ;
  float* VBT  = p; p += (long)NH*40*LSEQ;       // 245760
  float* LG   = p; p += (long)LSEQ*NH*LSEQ;     // 3.1M
  float* S1   = p; p += LSEQ*CS;
  // zero zone (single memset): P, T1, H1..H3, SH, OVT, SSUM (atomic targets)
  float* ZB   = p;
  float* P    = p; p += (long)LSEQ*NALL;
  float* T1   = p; p += LSEQ*CS;
  float* H1   = p; p += LSEQ*CS;
  float* H2   = p; p += LSEQ*CS;
  float* H3   = p; p += LSEQ*CS;
  float* SH   = p; p += (long)LSEQ*SHID;
  float* OVT  = p; p += (long)LSEQ*480;
  float* SSUM = p; p += LSEQ*16;
  size_t zbytes = ((size_t)LSEQ*NALL + 4*LSEQ*CS + (size_t)LSEQ*SHID
                   + (size_t)LSEQ*480 + LSEQ*16) * sizeof(float);

  hipMemsetAsync(ZB, 0, zbytes, stream);
  k_prep<<<1, 512, 0, stream>>>(quat, trsl, scale, Wb, R, T, CH, WBP);
  k_concat<<<(CS*NALL + 255)/256, 256, 0, stream>>>(Wq, Wk, Wv, Wqp, Wkp, Wvp, Wcat);
  // P = s @ Wcat  (split-K=2, atomic into zeroed P)
  k_gemm<<<dim3(NALL/64, LSEQ/64, 2), 256, 0, stream>>>(
      s, Wcat, P, nullptr, CS, CS, NALL, NALL, 2, 0, 0);
  k_trans<<<dim3(24, 3), 256, 0, stream>>>(P, R, T, QPP, KT, KPT, VBT);
  k_logit<<<LSEQ, 512, 0, stream>>>(P, QPP, KT, KPT, CH, LG);
  k_fused<<<dim3(LSEQ, 2), 256, 0, stream>>>(z, WBP, LG, VBT, SH, OVT, SSUM);
  k_opnorm<<<LSEQ, 256, 0, stream>>>(SSUM, SH);
  k_ovp<<<(LSEQ*NH + 255)/256, 256, 0, stream>>>(OVT, SSUM, R, T, SH);
  // T1 = SH @ Ws + bs  (split-K=12)
  k_gemm<<<dim3(CS/64, LSEQ/64, 12), 256, 0, stream>>>(
      SH, Ws, T1, bs, SHID, SHID, CS, CS, 12, 0, 0);
  k_ln<<<LSEQ, CS, 0, stream>>>(s, T1, g1, b1, S1);
  // MLP: split-K=8, relu fused into next GEMM's A-read
  k_gemm<<<dim3(CS/64, LSEQ/64, 8), 256, 0, stream>>>(
      S1, Wm1, H1, bm1, CS, CS, CS, CS, 8, 0, 0);
  k_gemm<<<dim3(CS/64, LSEQ/64, 8), 256, 0, stream>>>(
      H1, Wm2, H2, bm2, CS, CS, CS, CS, 8, 0, 1);
  k_gemm<<<dim3(CS/64, LSEQ/64, 8), 256, 0, stream>>>(
      H2, Wm3, H3, bm3, CS, CS, CS, CS, 8, 0, 1);
  k_ln<<<LSEQ, CS, 0, stream>>>(S1, H3, g2, b2, out);
}

// Round 3
// 691.765 us; speedup vs baseline: 1.0101x; 1.0101x over previous
//
#include <hip/hip_runtime.h>
#include <math.h>

#define LSEQ 512
#define CS 384
#define CZ 256
#define HD 16
#define NH 12
#define NQ 4
#define NV 8
#define NALL 1152   // 192*3 + 144*2 + 288
#define SHID 3648   // NH * 304
#define OFF_Q 0
#define OFF_K 192
#define OFF_V 384
#define OFF_QP 576
#define OFF_KP 720
#define OFF_VP 864

#define WC_CONST 0.2357022603955158f  // sqrt(2/(9*4))
#define WL_CONST 0.5773502691896258f  // sqrt(1/3)

typedef __attribute__((ext_vector_type(8))) short bf16x8;
typedef __attribute__((ext_vector_type(4))) float f32x4;

__device__ __forceinline__ short f2bf(float f) {
  unsigned u = __builtin_bit_cast(unsigned, f);
  unsigned r = (u + 0x7FFF + ((u >> 16) & 1)) >> 16;
  return (short)r;
}

// ---------------- prep: R, t, c_h, padded bf16 Wb ----------------
__global__ void k_prep(const float* quat, const float* trsl, const float* scale,
                       const float* Wb, float* R, float* T, float* CH,
                       unsigned short* WBP) {
  int t = threadIdx.x;
  if (t < LSEQ) {
    float w = quat[t*4+0], x = quat[t*4+1], y = quat[t*4+2], z = quat[t*4+3];
    float inv = 1.0f / sqrtf(w*w + x*x + y*y + z*z);
    w *= inv; x *= inv; y *= inv; z *= inv;
    float* r = R + t*9;
    r[0] = 1.f - 2.f*(y*y + z*z); r[1] = 2.f*(x*y - w*z);       r[2] = 2.f*(x*z + w*y);
    r[3] = 2.f*(x*y + w*z);       r[4] = 1.f - 2.f*(x*x + z*z); r[5] = 2.f*(y*z - w*x);
    r[6] = 2.f*(x*z - w*y);       r[7] = 2.f*(y*z + w*x);       r[8] = 1.f - 2.f*(x*x + y*y);
    T[t*3+0] = trsl[t*3+0]; T[t*3+1] = trsl[t*3+1]; T[t*3+2] = trsl[t*3+2];
  }
  if (t < NH) {
    float sc = scale[t];
    float sp = (sc > 20.f) ? sc : logf(1.f + expf(sc));
    CH[t] = 0.5f * WC_CONST * sp;
  }
  if (t < CZ) {
    #pragma unroll
    for (int h = 0; h < 16; h++)
      WBP[t*16 + h] = (h < NH) ? (unsigned short)f2bf(Wb[t*NH + h]) : (unsigned short)0;
  }
}

// ---------------- concat weights ----------------
__global__ void k_concat(const float* Wq, const float* Wk, const float* Wv,
                         const float* Wqp, const float* Wkp, const float* Wvp,
                         float* Wcat) {
  int idx = blockIdx.x * 256 + threadIdx.x;
  if (idx >= CS * NALL) return;
  int r = idx / NALL, c = idx % NALL;
  float v;
  if (c < 192)       v = Wq [r*192 + c];
  else if (c < 384)  v = Wk [r*192 + (c-192)];
  else if (c < 576)  v = Wv [r*192 + (c-384)];
  else if (c < 720)  v = Wqp[r*144 + (c-576)];
  else if (c < 864)  v = Wkp[r*144 + (c-720)];
  else               v = Wvp[r*288 + (c-864)];
  Wcat[idx] = v;
}

// ---------------- f32 GEMM with register prefetch; N,M multiples of 64 ----------------
__global__ __launch_bounds__(256) void k_gemm(
    const float* A, const float* B, float* C, const float* bias,
    int K, int lda, int ldb, int ldc, int splitk, int relu, int reluA) {
  int ks = blockIdx.z;
  int Ksub = K / splitk;
  int kbeg = ks * Ksub, kend = kbeg + Ksub;

  __shared__ __align__(16) float As[16][68];
  __shared__ __align__(16) float Bs[16][68];
  int t = threadIdx.x;
  int m0 = blockIdx.y * 64, n0 = blockIdx.x * 64;
  int arow = t >> 2,  akq = (t & 3) * 4;
  int bkk  = t >> 4,  bnq = (t & 15) * 4;
  int ty = (t >> 4) * 4, tx = (t & 15) * 4;
  float acc[4][4];
  #pragma unroll
  for (int r = 0; r < 4; r++)
    #pragma unroll
    for (int c = 0; c < 4; c++) acc[r][c] = 0.f;

  const float* aptr  = A + (long)(m0 + arow) * lda + akq;
  const float* bbase = B + n0 + bnq;
  float4 av = *(const float4*)&aptr[kbeg];
  float4 bv = *(const float4*)&bbase[(long)(kbeg + bkk) * ldb];

  for (int kb = kbeg; kb < kend; kb += 16) {
    float4 a_cur = av, b_cur = bv;
    if (reluA) {
      a_cur.x = fmaxf(a_cur.x, 0.f); a_cur.y = fmaxf(a_cur.y, 0.f);
      a_cur.z = fmaxf(a_cur.z, 0.f); a_cur.w = fmaxf(a_cur.w, 0.f);
    }
    __syncthreads();
    As[akq+0][arow] = a_cur.x; As[akq+1][arow] = a_cur.y;
    As[akq+2][arow] = a_cur.z; As[akq+3][arow] = a_cur.w;
    *(float4*)&Bs[bkk][bnq] = b_cur;
    __syncthreads();
    if (kb + 16 < kend) {
      av = *(const float4*)&aptr[kb + 16];
      bv = *(const float4*)&bbase[(long)(kb + 16 + bkk) * ldb];
    }
    #pragma unroll
    for (int kk = 0; kk < 16; kk++) {
      float4 a4 = *(float4*)&As[kk][ty];
      float4 b4 = *(float4*)&Bs[kk][tx];
      acc[0][0] += a4.x*b4.x; acc[0][1] += a4.x*b4.y; acc[0][2] += a4.x*b4.z; acc[0][3] += a4.x*b4.w;
      acc[1][0] += a4.y*b4.x; acc[1][1] += a4.y*b4.y; acc[1][2] += a4.y*b4.z; acc[1][3] += a4.y*b4.w;
      acc[2][0] += a4.z*b4.x; acc[2][1] += a4.z*b4.y; acc[2][2] += a4.z*b4.z; acc[2][3] += a4.z*b4.w;
      acc[3][0] += a4.w*b4.x; acc[3][1] += a4.w*b4.y; acc[3][2] += a4.w*b4.z; acc[3][3] += a4.w*b4.w;
    }
  }

  if (splitk == 1) {
    #pragma unroll
    for (int r = 0; r < 4; r++) {
      int m = m0 + ty + r;
      #pragma unroll
      for (int c = 0; c < 4; c++) {
        int n = n0 + tx + c;
        float v = acc[r][c] + (bias ? bias[n] : 0.f);
        if (relu) v = fmaxf(v, 0.f);
        C[(long)m * ldc + n] = v;
      }
    }
  } else {
    #pragma unroll
    for (int r = 0; r < 4; r++) {
      int m = m0 + ty + r;
      #pragma unroll
      for (int c = 0; c < 4; c++) {
        int n = n0 + tx + c;
        float v = acc[r][c] + ((ks == 0 && bias) ? bias[n] : 0.f);
        atomicAdd(&C[(long)m * ldc + n], v);
      }
    }
  }
}

// ---------------- rigid transforms, 3 concurrent tasks ----------------
__global__ void k_trans(const float* P, const float* R, const float* T,
                        float* QPP, float* KT, float* KPT, float* VBT) {
  int task = blockIdx.y;
  int idx = blockIdx.x * 256 + threadIdx.x;
  if (idx >= LSEQ * NH) return;
  int h = idx / LSEQ, l = idx % LSEQ;
  const float* r = R + l*9;
  float t0 = T[l*3], t1 = T[l*3+1], t2 = T[l*3+2];
  const float* prow = P + (long)l * NALL;
  if (task == 0) {
    #pragma unroll
    for (int pq = 0; pq < NQ; pq++) {
      const float* x = prow + OFF_QP + h*12 + pq*3;
      float a = x[0], b = x[1], c = x[2];
      float* o = QPP + l*144 + h*12 + pq*3;
      o[0] = r[0]*a + r[1]*b + r[2]*c + t0;
      o[1] = r[3]*a + r[4]*b + r[5]*c + t1;
      o[2] = r[6]*a + r[7]*b + r[8]*c + t2;
    }
    #pragma unroll
    for (int d = 0; d < HD; d++)
      KT[(h*HD + d)*LSEQ + l] = prow[OFF_K + h*HD + d];
  } else if (task == 1) {
    #pragma unroll
    for (int pq = 0; pq < NQ; pq++) {
      const float* x = prow + OFF_KP + h*12 + pq*3;
      float a = x[0], b = x[1], c = x[2];
      KPT[(h*12 + pq*3 + 0)*LSEQ + l] = r[0]*a + r[1]*b + r[2]*c + t0;
      KPT[(h*12 + pq*3 + 1)*LSEQ + l] = r[3]*a + r[4]*b + r[5]*c + t1;
      KPT[(h*12 + pq*3 + 2)*LSEQ + l] = r[6]*a + r[7]*b + r[8]*c + t2;
    }
  } else {
    #pragma unroll
    for (int d = 0; d < 16; d++)
      VBT[((long)(h*40 + d))*LSEQ + l] = prow[OFF_V + h*16 + d];
    #pragma unroll
    for (int pv = 0; pv < NV; pv++) {
      const float* x = prow + OFF_VP + h*24 + pv*3;
      float a = x[0], b = x[1], c = x[2];
      VBT[((long)(h*40 + 16 + 3*pv + 0))*LSEQ + l] = r[0]*a + r[1]*b + r[2]*c + t0;
      VBT[((long)(h*40 + 16 + 3*pv + 1))*LSEQ + l] = r[3]*a + r[4]*b + r[5]*c + t1;
      VBT[((long)(h*40 + 16 + 3*pv + 2))*LSEQ + l] = r[6]*a + r[7]*b + r[8]*c + t2;
    }
  }
}

// ---------------- mega-fused: logits + bias-MFMA + softmax + op/ov/ovp + epilogue ----
// grid 512 (one i per block), 512 threads (8 waves).
// Group g = t>>8 handles j-half g (waves 0-3 / 4-7). Per-group ping-pong es
// buffers -> ONE barrier per 64-j tile. Block-local totals -> no atomics, and
// the k_logit / k_opnorm / k_ovp work is folded in.
__global__ __launch_bounds__(512) void k_fused512(
    const float* zin, const unsigned short* WBP, const float* P,
    const float* QPP, const float* KT, const float* KPT, const float* CH,
    const float* VBT, const float* R, const float* T, float* SH) {
  // smem map (floats): lgs[12][516]=6192 | es[2][2][12][68]=3264 | pad | sred[8][16] | ssumv[16]
  __shared__ __align__(16) float smem[12864];
  float (*lgs)[516] = (float (*)[516])smem;
  float (*es)[2][NH][68] = (float (*)[2][NH][68])(smem + 6192);
  float* sred   = smem + 6192 + 6528;
  float* ssumv  = sred + 128;
  float* red_op = smem + 6192;          // overlay on es after main loop (3072)
  float* red_v  = smem + 6192 + 3072;   // overlay (480)

  int i = blockIdx.x, t = threadIdx.x;
  int g = t >> 8;            // j-half group
  int w8 = t >> 6;           // wave id 0..7
  int wg = w8 & 3;           // wave within group
  int l = t & 63, r = l & 15, kg = l >> 4;
  int cidx = t & 255;        // z-column / thread-in-group
  int hh = (r < NH) ? r : 0;

  // ---- phase 0: logits (ex-k_logit) straight into LDS ----
  {
    int j = t;
    const float* qb  = P + (long)i*NALL + OFF_Q;
    const float* qpb = QPP + i*144;
    #pragma unroll 2
    for (int h = 0; h < NH; h++) {
      float kreg[16];
      #pragma unroll
      for (int d = 0; d < 16; d++) kreg[d] = KT[(h*16 + d)*LSEQ + j];
      float kp[12];
      #pragma unroll
      for (int p = 0; p < 12; p++) kp[p] = KPT[(h*12 + p)*LSEQ + j];
      float ch = CH[h];
      const float* q  = qb + h*HD;     // i-uniform -> s_load
      const float* qp = qpb + h*12;    // i-uniform -> s_load
      float dot = 0.f;
      #pragma unroll
      for (int d = 0; d < 16; d++) dot += q[d] * kreg[d];
      float d2 = 0.f;
      #pragma unroll
      for (int p = 0; p < 12; p++) { float dd = qp[p] - kp[p]; d2 += dd*dd; }
      lgs[h][j] = WL_CONST * (0.25f*dot - ch*d2);
    }
  }

  // Wb B-frags (col h = r, k = kg*8+jj within kt*32 chunk)
  bf16x8 bfrag[8];
  #pragma unroll
  for (int kt = 0; kt < 8; kt++)
    #pragma unroll
    for (int jj = 0; jj < 8; jj++)
      bfrag[kt][jj] = (short)WBP[(kt*32 + kg*8 + jj)*16 + r];

  float accop[NH];
  #pragma unroll
  for (int h = 0; h < NH; h++) accop[h] = 0.f;
  int pair0 = cidx, pair1 = cidx + 256;       // (h,p) flat, 480 total
  int h0 = pair0 / 40, h1 = pair1 / 40;
  float accv0 = 0.f, accv1 = 0.f;
  float sparts = 0.f;

  __syncthreads();   // lgs ready

  int buf = 0;
  for (int step = 0; step < 4; step++) {
    int jt = step * 64;
    int j0 = g*256 + jt + wg*16;       // global j of this wave's MFMA rows
    // ---- MFMA phase: b for rows j0..j0+15, col h=r ----
    const float* zrow = zin + ((long)i*LSEQ + j0 + r)*CZ + kg*8;
    f32x4 acc = {0.f, 0.f, 0.f, 0.f};
    #pragma unroll
    for (int kt = 0; kt < 8; kt++) {
      float4 z0 = *(const float4*)(zrow + kt*32);
      float4 z1 = *(const float4*)(zrow + kt*32 + 4);
      bf16x8 af;
      af[0] = f2bf(z0.x); af[1] = f2bf(z0.y); af[2] = f2bf(z0.z); af[3] = f2bf(z0.w);
      af[4] = f2bf(z1.x); af[5] = f2bf(z1.y); af[6] = f2bf(z1.z); af[7] = f2bf(z1.w);
      acc = __builtin_amdgcn_mfma_f32_16x16x32_bf16(af, bfrag[kt], acc, 0, 0, 0);
    }
    // e = exp(LG + WL*b); D-layout: col h=r, row j = j0 + kg*4 + reg
    float4 lgv = *(float4*)&lgs[hh][j0 + kg*4];
    float e0 = __expf(lgv.x + WL_CONST*acc[0]);
    float e1 = __expf(lgv.y + WL_CONST*acc[1]);
    float e2 = __expf(lgv.z + WL_CONST*acc[2]);
    float e3 = __expf(lgv.w + WL_CONST*acc[3]);
    if (r < NH) {
      sparts += e0 + e1 + e2 + e3;
      *(float4*)&es[g][buf][r][wg*16 + kg*4] = make_float4(e0, e1, e2, e3);
    }
    __syncthreads();   // es[g][buf] ready (single barrier per tile; ping-pong)
    // ---- op phase: c = cidx, z re-read (L2-hot) ----
    const float* zc = zin + ((long)i*LSEQ + g*256 + jt)*CZ + cidx;
    #pragma unroll 4
    for (int jj = 0; jj < 64; jj += 4) {
      float z0 = zc[(jj+0)*CZ], z1 = zc[(jj+1)*CZ];
      float z2 = zc[(jj+2)*CZ], z3 = zc[(jj+3)*CZ];
      #pragma unroll
      for (int h = 0; h < NH; h++) {
        float4 ev = *(float4*)&es[g][buf][h][jj];
        accop[h] += ev.x*z0 + ev.y*z1 + ev.z*z2 + ev.w*z3;
      }
    }
    // ---- ovt phase ----
    {
      const float* vb0 = VBT + ((long)pair0)*LSEQ + g*256 + jt;
      #pragma unroll
      for (int jj = 0; jj < 64; jj += 4) {
        float4 vv = *(const float4*)&vb0[jj];
        float4 ev = *(float4*)&es[g][buf][h0][jj];
        accv0 += vv.x*ev.x + vv.y*ev.y + vv.z*ev.z + vv.w*ev.w;
      }
      if (pair1 < 480) {
        const float* vb1 = VBT + ((long)pair1)*LSEQ + g*256 + jt;
        #pragma unroll
        for (int jj = 0; jj < 64; jj += 4) {
          float4 vv = *(const float4*)&vb1[jj];
          float4 ev = *(float4*)&es[g][buf][h1][jj];
          accv1 += vv.x*ev.x + vv.y*ev.y + vv.z*ev.z + vv.w*ev.w;
        }
      }
    }
    buf ^= 1;   // next tile writes the other buffer; no second barrier needed
  }

  // ---- denominators ----
  sparts += __shfl_xor(sparts, 16);
  sparts += __shfl_xor(sparts, 32);
  if (l < NH) sred[w8*16 + l] = sparts;
  __syncthreads();   // sred ready; all es reads done -> overlay safe

  if (g == 1) {
    #pragma unroll
    for (int h = 0; h < NH; h++) red_op[h*256 + cidx] = accop[h];
    red_v[pair0] = accv0;
    if (pair1 < 480) red_v[pair1] = accv1;
  }
  if (t < NH) {
    float sv = 0.f;
    #pragma unroll
    for (int u = 0; u < 8; u++) sv += sred[u*16 + t];
    ssumv[t] = 1.0f / sv;
  }
  __syncthreads();   // red_* and ssumv ready

  if (g == 0) {
    float* sh = SH + (long)i * SHID + cidx;
    #pragma unroll
    for (int h = 0; h < NH; h++)
      sh[h * 304] = (accop[h] + red_op[h*256 + cidx]) * ssumv[h];
    float v0 = (accv0 + red_v[pair0]) * ssumv[h0];
    red_v[pair0] = v0;                       // same-slot rewrite: no hazard
    if (pair1 < 480) {
      float v1 = (accv1 + red_v[pair1]) * ssumv[h1];
      red_v[pair1] = v1;
    }
  }
  __syncthreads();   // normalized ov totals ready in red_v

  // ---- epilogue (ex-k_ovp): inverse transform + norm ----
  if (t < NH) {
    int h = t;
    const float* rr = R + i*9;
    float t0 = T[i*3], t1 = T[i*3+1], t2 = T[i*3+2];
    float* sh = SH + (long)i * SHID + h*304;
    const float* o = red_v + h*40;
    #pragma unroll
    for (int d = 0; d < 16; d++) sh[256 + d] = o[d];
    #pragma unroll
    for (int v = 0; v < NV; v++) {
      float a = o[16+3*v+0] - t0, b = o[16+3*v+1] - t1, c = o[16+3*v+2] - t2;
      float x = rr[0]*a + rr[3]*b + rr[6]*c;   // R^T
      float y = rr[1]*a + rr[4]*b + rr[7]*c;
      float zz= rr[2]*a + rr[5]*b + rr[8]*c;
      sh[272 + 3*v + 0] = x;
      sh[272 + 3*v + 1] = y;
      sh[272 + 3*v + 2] = zz;
      sh[296 + v] = sqrtf(x*x + y*y + zz*zz);
    }
  }
}

// ---------------- layernorm: out = LN(res + y) * g + b ----------------
__global__ __launch_bounds__(384) void k_ln(const float* res, const float* y,
                                            const float* g, const float* b, float* out) {
  int l = blockIdx.x, t = threadIdx.x;
  __shared__ float red1[6], red2[6];
  __shared__ float mv[2];
  float x = res[(long)l * CS + t] + y[(long)l * CS + t];
  float s = x, s2 = x * x;
  #pragma unroll
  for (int off = 32; off >= 1; off >>= 1) { s += __shfl_xor(s, off); s2 += __shfl_xor(s2, off); }
  if ((t & 63) == 0) { red1[t >> 6] = s; red2[t >> 6] = s2; }
  __syncthreads();
  if (t == 0) {
    float ss = 0.f, ss2 = 0.f;
    #pragma unroll
    for (int u = 0; u < 6; u++) { ss += red1[u]; ss2 += red2[u]; }
    float m = ss / CS;
    float var = ss2 / CS - m * m;
    mv[0] = m; mv[1] = 1.0f / sqrtf(var + 1e-5f);
  }
  __syncthreads();
  out[(long)l * CS + t] = (x - mv[0]) * mv[1] * g[t] + b[t];
}

// ---------------- launcher ----------------
extern "C" void kernel_launch(void* const* d_in, const int* in_sizes, int n_in,
                              void* d_out, int out_size, void* d_ws, size_t ws_size,
                              hipStream_t stream) {
  const float* s    = (const float*)d_in[0];
  const float* z    = (const float*)d_in[1];
  const float* quat = (const float*)d_in[2];
  const float* trsl = (const float*)d_in[3];
  const float* Wq   = (const float*)d_in[4];
  const float* Wk   = (const float*)d_in[5];
  const float* Wv   = (const float*)d_in[6];
  const float* Wqp  = (const float*)d_in[7];
  const float* Wkp  = (const float*)d_in[8];
  const float* Wvp  = (const float*)d_in[9];
  const float* Wb   = (const float*)d_in[10];
  const float* Ws   = (const float*)d_in[11];
  const float* bs   = (const float*)d_in[12];
  const float* scale= (const float*)d_in[13];
  const float* g1   = (const float*)d_in[14];
  const float* b1   = (const float*)d_in[15];
  const float* Wm1  = (const float*)d_in[16];
  const float* bm1  = (const float*)d_in[17];
  const float* Wm2  = (const float*)d_in[18];
  const float* bm2  = (const float*)d_in[19];
  const float* Wm3  = (const float*)d_in[20];
  const float* bm3  = (const float*)d_in[21];
  const float* g2   = (const float*)d_in[22];
  const float* b2   = (const float*)d_in[23];
  float* out = (float*)d_out;

  float* p = (float*)d_ws;
  float* R    = p; p += 512*9;
  float* T    = p; p += 512*3;
  float* CH   = p; p += 16;
  unsigned short* WBP = (unsigned short*)p; p += (CZ*16)/2;
  float* Wcat = p; p += (long)CS*NALL;
  float* QPP  = p; p += LSEQ*144;
  float* KT   = p; p += NH*HD*LSEQ;
  float* KPT  = p; p += NH*12*LSEQ;
  float* VBT  = p; p += (long)NH*40*LSEQ;       // 245760
  float* SH   = p; p += (long)LSEQ*SHID;        // fully written by k_fused512
  float* S1   = p; p += LSEQ*CS;
  // zero zone (single memset): P, T1, H1..H3 (split-K atomic targets)
  float* ZB   = p;
  float* P    = p; p += (long)LSEQ*NALL;
  float* T1   = p; p += LSEQ*CS;
  float* H1   = p; p += LSEQ*CS;
  float* H2   = p; p += LSEQ*CS;
  float* H3   = p; p += LSEQ*CS;
  size_t zbytes = ((size_t)LSEQ*NALL + 4*LSEQ*CS) * sizeof(float);

  hipMemsetAsync(ZB, 0, zbytes, stream);
  k_prep<<<1, 512, 0, stream>>>(quat, trsl, scale, Wb, R, T, CH, WBP);
  k_concat<<<(CS*NALL + 255)/256, 256, 0, stream>>>(Wq, Wk, Wv, Wqp, Wkp, Wvp, Wcat);
  // P = s @ Wcat  (split-K=2, atomic into zeroed P)
  k_gemm<<<dim3(NALL/64, LSEQ/64, 2), 256, 0, stream>>>(
      s, Wcat, P, nullptr, CS, CS, NALL, NALL, 2, 0, 0);
  k_trans<<<dim3(24, 3), 256, 0, stream>>>(P, R, T, QPP, KT, KPT, VBT);
  k_fused512<<<LSEQ, 512, 0, stream>>>(z, WBP, P, QPP, KT, KPT, CH, VBT, R, T, SH);
  // T1 = SH @ Ws + bs  (split-K=12)
  k_gemm<<<dim3(CS/64, LSEQ/64, 12), 256, 0, stream>>>(
      SH, Ws, T1, bs, SHID, SHID, CS, CS, 12, 0, 0);
  k_ln<<<LSEQ, CS, 0, stream>>>(s, T1, g1, b1, S1);
  // MLP: split-K=8, relu fused into next GEMM's A-read
  k_gemm<<<dim3(CS/64, LSEQ/64, 8), 256, 0, stream>>>(
      S1, Wm1, H1, bm1, CS, CS, CS, CS, 8, 0, 0);
  k_gemm<<<dim3(CS/64, LSEQ/64, 8), 256, 0, stream>>>(
      H1, Wm2, H2, bm2, CS, CS, CS, CS, 8, 0, 1);
  k_gemm<<<dim3(CS/64, LSEQ/64, 8), 256, 0, stream>>>(
      H2, Wm3, H3, bm3, CS, CS, CS, CS, 8, 0, 1);
  k_ln<<<LSEQ, CS, 0, stream>>>(S1, H3, g2, b2, out);
}

// Round 4
// 639.606 us; speedup vs baseline: 1.0925x; 1.0815x over previous
//
#include <hip/hip_runtime.h>
#include <math.h>

#define LSEQ 512
#define CS 384
#define CZ 256
#define HD 16
#define NH 12
#define NQ 4
#define NV 8
#define NALL 1152   // 192*3 + 144*2 + 288
#define SHID 3648   // NH * 304
#define OFF_Q 0
#define OFF_K 192
#define OFF_V 384
#define OFF_QP 576
#define OFF_KP 720
#define OFF_VP 864

#define WC_CONST 0.2357022603955158f  // sqrt(2/(9*4))
#define WL_CONST 0.5773502691896258f  // sqrt(1/3)

typedef __attribute__((ext_vector_type(8))) short bf16x8;
typedef __attribute__((ext_vector_type(4))) float f32x4;

__device__ __forceinline__ short f2bf(float f) {
  unsigned u = __builtin_bit_cast(unsigned, f);
  unsigned r = (u + 0x7FFF + ((u >> 16) & 1)) >> 16;
  return (short)r;
}

// ---------------- prep: R, t, c_h, padded bf16 Wb ----------------
__global__ void k_prep(const float* quat, const float* trsl, const float* scale,
                       const float* Wb, float* R, float* T, float* CH,
                       unsigned short* WBP) {
  int t = threadIdx.x;
  if (t < LSEQ) {
    float w = quat[t*4+0], x = quat[t*4+1], y = quat[t*4+2], z = quat[t*4+3];
    float inv = 1.0f / sqrtf(w*w + x*x + y*y + z*z);
    w *= inv; x *= inv; y *= inv; z *= inv;
    float* r = R + t*9;
    r[0] = 1.f - 2.f*(y*y + z*z); r[1] = 2.f*(x*y - w*z);       r[2] = 2.f*(x*z + w*y);
    r[3] = 2.f*(x*y + w*z);       r[4] = 1.f - 2.f*(x*x + z*z); r[5] = 2.f*(y*z - w*x);
    r[6] = 2.f*(x*z - w*y);       r[7] = 2.f*(y*z + w*x);       r[8] = 1.f - 2.f*(x*x + y*y);
    T[t*3+0] = trsl[t*3+0]; T[t*3+1] = trsl[t*3+1]; T[t*3+2] = trsl[t*3+2];
  }
  if (t < NH) {
    float sc = scale[t];
    float sp = (sc > 20.f) ? sc : logf(1.f + expf(sc));
    CH[t] = 0.5f * WC_CONST * sp;
  }
  if (t < CZ) {
    #pragma unroll
    for (int h = 0; h < 16; h++)
      WBP[t*16 + h] = (h < NH) ? (unsigned short)f2bf(Wb[t*NH + h]) : (unsigned short)0;
  }
}

// ---------------- concat weights (f32 [K=384][N=1152]) ----------------
__global__ void k_concat(const float* Wq, const float* Wk, const float* Wv,
                         const float* Wqp, const float* Wkp, const float* Wvp,
                         float* Wcat) {
  int idx = blockIdx.x * 256 + threadIdx.x;
  if (idx >= CS * NALL) return;
  int r = idx / NALL, c = idx % NALL;
  float v;
  if (c < 192)       v = Wq [r*192 + c];
  else if (c < 384)  v = Wk [r*192 + (c-192)];
  else if (c < 576)  v = Wv [r*192 + (c-384)];
  else if (c < 720)  v = Wqp[r*144 + (c-576)];
  else if (c < 864)  v = Wkp[r*144 + (c-720)];
  else               v = Wvp[r*288 + (c-864)];
  Wcat[idx] = v;
}

// ---------------- transpose+split all weights to bf16 hi/lo planes [N][K] ----
// tasks: 0 Wcat(384x1152, 108 tiles) 1 Ws(3648x384, 342) 2..4 Wm*(384x384, 36 each)
__global__ __launch_bounds__(256) void k_cvtall(
    const float* Wcat, const float* Ws, const float* Wm1, const float* Wm2, const float* Wm3,
    unsigned short* WcatH, unsigned short* WcatL,
    unsigned short* WsH, unsigned short* WsL,
    unsigned short* Wm1H, unsigned short* Wm1L,
    unsigned short* Wm2H, unsigned short* Wm2L,
    unsigned short* Wm3H, unsigned short* Wm3L) {
  int tb = blockIdx.x;
  const float* src; unsigned short *dh, *dl; int K, N, tile;
  if (tb < 108)      { src=Wcat; dh=WcatH; dl=WcatL; K=384;  N=1152; tile=tb; }
  else if (tb < 450) { src=Ws;   dh=WsH;   dl=WsL;   K=3648; N=384;  tile=tb-108; }
  else if (tb < 486) { src=Wm1;  dh=Wm1H;  dl=Wm1L;  K=384;  N=384;  tile=tb-450; }
  else if (tb < 522) { src=Wm2;  dh=Wm2H;  dl=Wm2L;  K=384;  N=384;  tile=tb-486; }
  else               { src=Wm3;  dh=Wm3H;  dl=Wm3L;  K=384;  N=384;  tile=tb-522; }
  int tN = N >> 6;
  int k0 = (tile / tN) * 64, n0 = (tile % tN) * 64;
  __shared__ float ts[64][65];
  int t = threadIdx.x;
  int cr = t & 63, rr = t >> 6;
  #pragma unroll
  for (int u = 0; u < 16; u++) {
    int row = rr + u*4;
    ts[row][cr] = src[(long)(k0+row)*N + n0 + cr];
  }
  __syncthreads();
  #pragma unroll
  for (int u = 0; u < 16; u++) {
    int nr = rr + u*4;
    float v = ts[cr][nr];
    unsigned uv = __builtin_bit_cast(unsigned, v);
    unsigned short h = (unsigned short)(uv >> 16);
    float hf = __builtin_bit_cast(float, uv & 0xFFFF0000u);
    float lf = v - hf;
    unsigned short lo = (unsigned short)(__builtin_bit_cast(unsigned, lf) >> 16);
    long o = (long)(n0+nr)*K + k0 + cr;
    dh[o] = h; dl[o] = lo;
  }
}

// ---------------- MFMA GEMM, hi/lo bf16 split, no LDS, no barriers ----------
// C[M=512 x N] = A[512 x K] @ B[K x N]; B pre-split as [N][K] hi/lo planes.
// grid (N/64, 512/64, splitk), 256 threads. Wave w owns rows m0..m0+15.
// Fragment layout (verified via k_fused): A row=lane&15, k=(lane>>4)*8+e;
// B col=lane&15, same k; D col=lane&15, row=(lane>>4)*4+reg.
__global__ __launch_bounds__(256) void k_gemm_bb(
    const float* A, const unsigned short* Bh, const unsigned short* Bl,
    float* C, const float* bias, int K, int N, int splitk, int reluA) {
  int t = threadIdx.x;
  int w = t >> 6, lane = t & 63, r = lane & 15, kg = lane >> 4;
  int m0 = blockIdx.y * 64 + w * 16;
  int n0 = blockIdx.x * 64;
  int Ksub = K / splitk;
  int kbeg = blockIdx.z * Ksub, kend = kbeg + Ksub;

  f32x4 acc[4];
  #pragma unroll
  for (int nt = 0; nt < 4; nt++) acc[nt] = (f32x4){0.f, 0.f, 0.f, 0.f};

  const float* arow = A + (long)(m0 + r) * K + kg*8;
  const unsigned short* bhp[4];
  const unsigned short* blp[4];
  #pragma unroll
  for (int nt = 0; nt < 4; nt++) {
    long off = (long)(n0 + nt*16 + r) * K + kg*8;
    bhp[nt] = Bh + off;
    blp[nt] = Bl + off;
  }

  for (int kc = kbeg; kc < kend; kc += 32) {
    float4 a0 = *(const float4*)&arow[kc];
    float4 a1 = *(const float4*)&arow[kc + 4];
    if (reluA) {
      a0.x = fmaxf(a0.x, 0.f); a0.y = fmaxf(a0.y, 0.f);
      a0.z = fmaxf(a0.z, 0.f); a0.w = fmaxf(a0.w, 0.f);
      a1.x = fmaxf(a1.x, 0.f); a1.y = fmaxf(a1.y, 0.f);
      a1.z = fmaxf(a1.z, 0.f); a1.w = fmaxf(a1.w, 0.f);
    }
    float av[8] = {a0.x, a0.y, a0.z, a0.w, a1.x, a1.y, a1.z, a1.w};
    bf16x8 ah, al;
    #pragma unroll
    for (int e = 0; e < 8; e++) {
      unsigned uv = __builtin_bit_cast(unsigned, av[e]);
      ah[e] = (short)(uv >> 16);
      float hf = __builtin_bit_cast(float, uv & 0xFFFF0000u);
      al[e] = (short)(__builtin_bit_cast(unsigned, av[e] - hf) >> 16);
    }
    #pragma unroll
    for (int nt = 0; nt < 4; nt++) {
      bf16x8 bh = *(const bf16x8*)&bhp[nt][kc];
      bf16x8 bl = *(const bf16x8*)&blp[nt][kc];
      acc[nt] = __builtin_amdgcn_mfma_f32_16x16x32_bf16(ah, bh, acc[nt], 0, 0, 0);
      acc[nt] = __builtin_amdgcn_mfma_f32_16x16x32_bf16(al, bh, acc[nt], 0, 0, 0);
      acc[nt] = __builtin_amdgcn_mfma_f32_16x16x32_bf16(ah, bl, acc[nt], 0, 0, 0);
    }
  }

  bool add_bias = (bias != nullptr) && (blockIdx.z == 0);
  #pragma unroll
  for (int nt = 0; nt < 4; nt++) {
    int n = n0 + nt*16 + r;
    float bv = add_bias ? bias[n] : 0.f;
    #pragma unroll
    for (int reg = 0; reg < 4; reg++) {
      int m = m0 + kg*4 + reg;
      float v = acc[nt][reg] + bv;
      if (splitk == 1) C[(long)m * N + n] = v;
      else atomicAdd(&C[(long)m * N + n], v);
    }
  }
}

// ---------------- rigid transforms, 3 concurrent tasks ----------------
__global__ void k_trans(const float* P, const float* R, const float* T,
                        float* QPP, float* KT, float* KPT, float* VBT) {
  int task = blockIdx.y;
  int idx = blockIdx.x * 256 + threadIdx.x;
  if (idx >= LSEQ * NH) return;
  int h = idx / LSEQ, l = idx % LSEQ;
  const float* r = R + l*9;
  float t0 = T[l*3], t1 = T[l*3+1], t2 = T[l*3+2];
  const float* prow = P + (long)l * NALL;
  if (task == 0) {
    #pragma unroll
    for (int pq = 0; pq < NQ; pq++) {
      const float* x = prow + OFF_QP + h*12 + pq*3;
      float a = x[0], b = x[1], c = x[2];
      float* o = QPP + l*144 + h*12 + pq*3;
      o[0] = r[0]*a + r[1]*b + r[2]*c + t0;
      o[1] = r[3]*a + r[4]*b + r[5]*c + t1;
      o[2] = r[6]*a + r[7]*b + r[8]*c + t2;
    }
    #pragma unroll
    for (int d = 0; d < HD; d++)
      KT[(h*HD + d)*LSEQ + l] = prow[OFF_K + h*HD + d];
  } else if (task == 1) {
    #pragma unroll
    for (int pq = 0; pq < NQ; pq++) {
      const float* x = prow + OFF_KP + h*12 + pq*3;
      float a = x[0], b = x[1], c = x[2];
      KPT[(h*12 + pq*3 + 0)*LSEQ + l] = r[0]*a + r[1]*b + r[2]*c + t0;
      KPT[(h*12 + pq*3 + 1)*LSEQ + l] = r[3]*a + r[4]*b + r[5]*c + t1;
      KPT[(h*12 + pq*3 + 2)*LSEQ + l] = r[6]*a + r[7]*b + r[8]*c + t2;
    }
  } else {
    #pragma unroll
    for (int d = 0; d < 16; d++)
      VBT[((long)(h*40 + d))*LSEQ + l] = prow[OFF_V + h*16 + d];
    #pragma unroll
    for (int pv = 0; pv < NV; pv++) {
      const float* x = prow + OFF_VP + h*24 + pv*3;
      float a = x[0], b = x[1], c = x[2];
      VBT[((long)(h*40 + 16 + 3*pv + 0))*LSEQ + l] = r[0]*a + r[1]*b + r[2]*c + t0;
      VBT[((long)(h*40 + 16 + 3*pv + 1))*LSEQ + l] = r[3]*a + r[4]*b + r[5]*c + t1;
      VBT[((long)(h*40 + 16 + 3*pv + 2))*LSEQ + l] = r[6]*a + r[7]*b + r[8]*c + t2;
    }
  }
}

// ---------------- fused: inline logits + bias-MFMA + softmax + op/ov/ovp -----
// grid (512, 2), 256 threads (4 waves). Each block: one i, one j-half (256 j).
// Unnormalized partials accumulate via atomicAdd into zeroed SH/OVT/SSUM.
__global__ __launch_bounds__(256) void k_fused(const float* zin,
    const unsigned short* WBP, const float* P, const float* QPP,
    const float* KT, const float* KPT, const float* CH, const float* VBT,
    float* SH, float* OVT, float* SSUM) {
  __shared__ __align__(16) float lgs[NH][264];
  __shared__ __align__(16) float es[NH][68];
  __shared__ float sred[4][NH];
  int i = blockIdx.x, js = blockIdx.y, t = threadIdx.x;
  int jbase = js * 256;
  int w = t >> 6, l = t & 63;
  int r = l & 15, kg = l >> 4;
  int hh = (r < NH) ? r : 0;

  // ---- inline logits (ex-k_logit) for this block's 256 j's ----
  {
    int j = jbase + t;
    const float* qb  = P + (long)i*NALL + OFF_Q;
    const float* qpb = QPP + i*144;
    #pragma unroll 2
    for (int h = 0; h < NH; h++) {
      float kreg[16];
      #pragma unroll
      for (int d = 0; d < 16; d++) kreg[d] = KT[(h*16 + d)*LSEQ + j];
      float kp[12];
      #pragma unroll
      for (int p = 0; p < 12; p++) kp[p] = KPT[(h*12 + p)*LSEQ + j];
      float ch = CH[h];
      const float* q  = qb + h*HD;     // i-uniform -> s_load
      const float* qp = qpb + h*12;    // i-uniform -> s_load
      float dot = 0.f;
      #pragma unroll
      for (int d = 0; d < 16; d++) dot += q[d] * kreg[d];
      float d2 = 0.f;
      #pragma unroll
      for (int p = 0; p < 12; p++) { float dd = qp[p] - kp[p]; d2 += dd*dd; }
      lgs[h][t] = WL_CONST * (0.25f*dot - ch*d2);
    }
  }

  // Wb B-frags (col h = r, k = kg*8+jj within kt*32 chunk)
  bf16x8 bfrag[8];
  #pragma unroll
  for (int kt = 0; kt < 8; kt++)
    #pragma unroll
    for (int jj = 0; jj < 8; jj++)
      bfrag[kt][jj] = (short)WBP[(kt*32 + kg*8 + jj)*16 + r];

  float accop[NH];
  #pragma unroll
  for (int h = 0; h < NH; h++) accop[h] = 0.f;
  int pair0 = t, pair1 = t + 256;             // (h,p) flat, 480 total
  int h0 = pair0 / 40, h1 = pair1 / 40;
  float accv0 = 0.f, accv1 = 0.f;
  float sparts = 0.f;

  __syncthreads();   // lgs ready

  for (int jt = 0; jt < 256; jt += 64) {
    int j0 = jt + w*16;            // local j of this wave's MFMA rows
    int j0g = jbase + j0;          // global j for z reads
    // ---- MFMA phase: b for rows j0g..j0g+15, col h=r ----
    const float* zrow = zin + ((long)i*LSEQ + j0g + r)*CZ + kg*8;
    f32x4 acc = {0.f, 0.f, 0.f, 0.f};
    #pragma unroll
    for (int kt = 0; kt < 8; kt++) {
      float4 z0 = *(const float4*)(zrow + kt*32);
      float4 z1 = *(const float4*)(zrow + kt*32 + 4);
      bf16x8 af;
      af[0] = f2bf(z0.x); af[1] = f2bf(z0.y); af[2] = f2bf(z0.z); af[3] = f2bf(z0.w);
      af[4] = f2bf(z1.x); af[5] = f2bf(z1.y); af[6] = f2bf(z1.z); af[7] = f2bf(z1.w);
      acc = __builtin_amdgcn_mfma_f32_16x16x32_bf16(af, bfrag[kt], acc, 0, 0, 0);
    }
    // e = exp(LG + WL*b); D-layout: col h=r, row j = j0 + kg*4 + reg
    float4 lgv = *(float4*)&lgs[hh][j0 + kg*4];
    float e0 = __expf(lgv.x + WL_CONST*acc[0]);
    float e1 = __expf(lgv.y + WL_CONST*acc[1]);
    float e2 = __expf(lgv.z + WL_CONST*acc[2]);
    float e3 = __expf(lgv.w + WL_CONST*acc[3]);
    if (r < NH) {
      sparts += e0 + e1 + e2 + e3;
      *(float4*)&es[r][w*16 + kg*4] = make_float4(e0, e1, e2, e3);
    }
    __syncthreads();   // es ready
    // ---- op phase: c = t, z re-read (L2-hot) ----
    const float* zc = zin + ((long)i*LSEQ + jbase + jt)*CZ + t;
    #pragma unroll 4
    for (int jj = 0; jj < 64; jj += 4) {
      float z0 = zc[(jj+0)*CZ], z1 = zc[(jj+1)*CZ];
      float z2 = zc[(jj+2)*CZ], z3 = zc[(jj+3)*CZ];
      #pragma unroll
      for (int h = 0; h < NH; h++) {
        float4 ev = *(float4*)&es[h][jj];
        accop[h] += ev.x*z0 + ev.y*z1 + ev.z*z2 + ev.w*z3;
      }
    }
    // ---- ovt phase ----
    {
      const float* vb0 = VBT + ((long)pair0)*LSEQ + jbase + jt;
      #pragma unroll
      for (int jj = 0; jj < 64; jj += 4) {
        float4 vv = *(const float4*)&vb0[jj];
        float4 ev = *(float4*)&es[h0][jj];
        accv0 += vv.x*ev.x + vv.y*ev.y + vv.z*ev.z + vv.w*ev.w;
      }
      if (pair1 < 480) {
        const float* vb1 = VBT + ((long)pair1)*LSEQ + jbase + jt;
        #pragma unroll
        for (int jj = 0; jj < 64; jj += 4) {
          float4 vv = *(const float4*)&vb1[jj];
          float4 ev = *(float4*)&es[h1][jj];
          accv1 += vv.x*ev.x + vv.y*ev.y + vv.z*ev.z + vv.w*ev.w;
        }
      }
    }
    __syncthreads();   // es consumed before next tile overwrites
  }

  // partial denominators -> SSUM (stride 16 per i)
  sparts += __shfl_xor(sparts, 16);
  sparts += __shfl_xor(sparts, 32);
  if (l < NH) sred[w][l] = sparts;
  __syncthreads();
  if (t < NH)
    atomicAdd(&SSUM[i*16 + t], sred[0][t] + sred[1][t] + sred[2][t] + sred[3][t]);

  // unnormalized partials
  float* sh = SH + (long)i * SHID + t;
  #pragma unroll
  for (int h = 0; h < NH; h++) atomicAdd(&sh[h * 304], accop[h]);
  atomicAdd(&OVT[(long)i*480 + pair0], accv0);
  if (pair1 < 480) atomicAdd(&OVT[(long)i*480 + pair1], accv1);
}

// ---------------- normalize op region of SH ----------------
__global__ __launch_bounds__(256) void k_opnorm(const float* SSUM, float* SH) {
  int i = blockIdx.x, t = threadIdx.x;
  float* sh = SH + (long)i * SHID + t;
  #pragma unroll
  for (int h = 0; h < NH; h++) {
    float inv = 1.0f / SSUM[i*16 + h];
    sh[h * 304] *= inv;
  }
}

// ---------------- ovp inverse transform + norm + shid fill ----------------
__global__ void k_ovp(const float* OVT, const float* SSUM, const float* R,
                      const float* T, float* SH) {
  int idx = blockIdx.x * 256 + threadIdx.x;
  if (idx >= LSEQ * NH) return;
  int l = idx / NH, h = idx % NH;
  float inv = 1.0f / SSUM[l*16 + h];
  const float* o = OVT + (long)l*480 + h*40;
  float* sh = SH + (long)l * SHID + h * 304;
  #pragma unroll
  for (int d = 0; d < 16; d++) sh[256 + d] = o[d] * inv;
  const float* r = R + l*9;
  float t0 = T[l*3], t1 = T[l*3+1], t2 = T[l*3+2];
  #pragma unroll
  for (int v = 0; v < NV; v++) {
    float a = o[16+3*v+0]*inv - t0, b = o[16+3*v+1]*inv - t1, c = o[16+3*v+2]*inv - t2;
    float x = r[0]*a + r[3]*b + r[6]*c;   // R^T
    float y = r[1]*a + r[4]*b + r[7]*c;
    float zz= r[2]*a + r[5]*b + r[8]*c;
    sh[272 + 3*v + 0] = x;
    sh[272 + 3*v + 1] = y;
    sh[272 + 3*v + 2] = zz;
    sh[296 + v] = sqrtf(x*x + y*y + zz*zz);
  }
}

// ---------------- layernorm: out = LN(res + y) * g + b ----------------
__global__ __launch_bounds__(384) void k_ln(const float* res, const float* y,
                                            const float* g, const float* b, float* out) {
  int l = blockIdx.x, t = threadIdx.x;
  __shared__ float red1[6], red2[6];
  __shared__ float mv[2];
  float x = res[(long)l * CS + t] + y[(long)l * CS + t];
  float s = x, s2 = x * x;
  #pragma unroll
  for (int off = 32; off >= 1; off >>= 1) { s += __shfl_xor(s, off); s2 += __shfl_xor(s2, off); }
  if ((t & 63) == 0) { red1[t >> 6] = s; red2[t >> 6] = s2; }
  __syncthreads();
  if (t == 0) {
    float ss = 0.f, ss2 = 0.f;
    #pragma unroll
    for (int u = 0; u < 6; u++) { ss += red1[u]; ss2 += red2[u]; }
    float m = ss / CS;
    float var = ss2 / CS - m * m;
    mv[0] = m; mv[1] = 1.0f / sqrtf(var + 1e-5f);
  }
  __syncthreads();
  out[(long)l * CS + t] = (x - mv[0]) * mv[1] * g[t] + b[t];
}

// ---------------- launcher ----------------
extern "C" void kernel_launch(void* const* d_in, const int* in_sizes, int n_in,
                              void* d_out, int out_size, void* d_ws, size_t ws_size,
                              hipStream_t stream) {
  const float* s    = (const float*)d_in[0];
  const float* z    = (const float*)d_in[1];
  const float* quat = (const float*)d_in[2];
  const float* trsl = (const float*)d_in[3];
  const float* Wq   = (const float*)d_in[4];
  const float* Wk   = (const float*)d_in[5];
  const float* Wv   = (const float*)d_in[6];
  const float* Wqp  = (const float*)d_in[7];
  const float* Wkp  = (const float*)d_in[8];
  const float* Wvp  = (const float*)d_in[9];
  const float* Wb   = (const float*)d_in[10];
  const float* Ws   = (const float*)d_in[11];
  const float* bs   = (const float*)d_in[12];
  const float* scale= (const float*)d_in[13];
  const float* g1   = (const float*)d_in[14];
  const float* b1   = (const float*)d_in[15];
  const float* Wm1  = (const float*)d_in[16];
  const float* bm1  = (const float*)d_in[17];
  const float* Wm2  = (const float*)d_in[18];
  const float* bm2  = (const float*)d_in[19];
  const float* Wm3  = (const float*)d_in[20];
  const float* bm3  = (const float*)d_in[21];
  const float* g2   = (const float*)d_in[22];
  const float* b2   = (const float*)d_in[23];
  float* out = (float*)d_out;

  float* p = (float*)d_ws;
  float* R    = p; p += 512*9;
  float* T    = p; p += 512*3;
  float* CH   = p; p += 16;
  unsigned short* WBP = (unsigned short*)p; p += (CZ*16)/2;
  float* Wcat = p; p += (long)CS*NALL;
  unsigned short* WcatH = (unsigned short*)p; p += (CS*NALL)/2;
  unsigned short* WcatL = (unsigned short*)p; p += (CS*NALL)/2;
  unsigned short* WsH   = (unsigned short*)p; p += (SHID*CS)/2;
  unsigned short* WsL   = (unsigned short*)p; p += (SHID*CS)/2;
  unsigned short* Wm1H  = (unsigned short*)p; p += (CS*CS)/2;
  unsigned short* Wm1L  = (unsigned short*)p; p += (CS*CS)/2;
  unsigned short* Wm2H  = (unsigned short*)p; p += (CS*CS)/2;
  unsigned short* Wm2L  = (unsigned short*)p; p += (CS*CS)/2;
  unsigned short* Wm3H  = (unsigned short*)p; p += (CS*CS)/2;
  unsigned short* Wm3L  = (unsigned short*)p; p += (CS*CS)/2;
  float* QPP  = p; p += LSEQ*144;
  float* KT   = p; p += NH*HD*LSEQ;
  float* KPT  = p; p += NH*12*LSEQ;
  float* VBT  = p; p += (long)NH*40*LSEQ;       // 245760
  float* S1   = p; p += LSEQ*CS;
  // zero zone (single memset): atomic targets
  float* ZB   = p;
  float* P    = p; p += (long)LSEQ*NALL;
  float* T1   = p; p += LSEQ*CS;
  float* H1   = p; p += LSEQ*CS;
  float* H2   = p; p += LSEQ*CS;
  float* H3   = p; p += LSEQ*CS;
  float* SH   = p; p += (long)LSEQ*SHID;
  float* OVT  = p; p += (long)LSEQ*480;
  float* SSUM = p; p += LSEQ*16;
  size_t zbytes = ((size_t)LSEQ*NALL + 4*LSEQ*CS + (size_t)LSEQ*SHID
                   + (size_t)LSEQ*480 + LSEQ*16) * sizeof(float);

  hipMemsetAsync(ZB, 0, zbytes, stream);
  k_prep<<<1, 512, 0, stream>>>(quat, trsl, scale, Wb, R, T, CH, WBP);
  k_concat<<<(CS*NALL + 255)/256, 256, 0, stream>>>(Wq, Wk, Wv, Wqp, Wkp, Wvp, Wcat);
  k_cvtall<<<558, 256, 0, stream>>>(Wcat, Ws, Wm1, Wm2, Wm3,
      WcatH, WcatL, WsH, WsL, Wm1H, Wm1L, Wm2H, Wm2L, Wm3H, Wm3L);
  // P = s @ Wcat  (MFMA hi/lo, split-K=4, atomic into zeroed P)
  k_gemm_bb<<<dim3(NALL/64, LSEQ/64, 4), 256, 0, stream>>>(
      s, WcatH, WcatL, P, nullptr, CS, NALL, 4, 0);
  k_trans<<<dim3(24, 3), 256, 0, stream>>>(P, R, T, QPP, KT, KPT, VBT);
  k_fused<<<dim3(LSEQ, 2), 256, 0, stream>>>(
      z, WBP, P, QPP, KT, KPT, CH, VBT, SH, OVT, SSUM);
  k_opnorm<<<LSEQ, 256, 0, stream>>>(SSUM, SH);
  k_ovp<<<(LSEQ*NH + 255)/256, 256, 0, stream>>>(OVT, SSUM, R, T, SH);
  // T1 = SH @ Ws + bs  (split-K=6, Ksub=608 -> 19 chunks)
  k_gemm_bb<<<dim3(CS/64, LSEQ/64, 6), 256, 0, stream>>>(
      SH, WsH, WsL, T1, bs, SHID, CS, 6, 0);
  k_ln<<<LSEQ, CS, 0, stream>>>(s, T1, g1, b1, S1);
  // MLP: relu fused into next GEMM's A-read
  k_gemm_bb<<<dim3(CS/64, LSEQ/64, 4), 256, 0, stream>>>(
      S1, Wm1H, Wm1L, H1, bm1, CS, CS, 4, 0);
  k_gemm_bb<<<dim3(CS/64, LSEQ/64, 4), 256, 0, stream>>>(
      H1, Wm2H, Wm2L, H2, bm2, CS, CS, 4, 1);
  k_gemm_bb<<<dim3(CS/64, LSEQ/64, 4), 256, 0, stream>>>(
      H2, Wm3H, Wm3L, H3, bm3, CS, CS, 4, 1);
  k_ln<<<LSEQ, CS, 0, stream>>>(S1, H3, g2, b2, out);
}